// Round 7
// baseline (114.425 us; speedup 1.0000x reference)
//
#include <hip/hip_runtime.h>
#include <cmath>

constexpr int B = 8, S = 128, F = 512, D = 256, FEAT = 80;
// Finite stand-in for -inf (see round-1 note: avoids nan in harness absmax).
#define NEG_HUGE (-3.0e38f)

typedef unsigned short u16;
typedef unsigned int u32;
typedef __attribute__((ext_vector_type(8))) short bf16x8;   // 8 bf16 = 4 VGPR
typedef __attribute__((ext_vector_type(4))) float f32x4;

// ---- bf16 split helpers ----
__device__ __forceinline__ u16 f2bf(float x) {
    u32 u = __float_as_uint(x);
    u32 r = (u + 0x7fffu + ((u >> 16) & 1u)) >> 16;   // RNE
    return (u16)r;
}
__device__ __forceinline__ float bf2f(u16 s) {
    return __uint_as_float(((u32)s) << 16);
}
__device__ __forceinline__ void split_store(float v, u16* __restrict__ hi,
                                            u16* __restrict__ lo, int idx) {
    u16 h = f2bf(v);
    hi[idx] = h;
    lo[idx] = f2bf(v - bf2f(h));
}

// ================= sizes =================
constexpr int PRF = F + 2;      // 514 padded feat rows
constexpr int PRH = S + 2;      // 130 padded text rows
constexpr int CIN_M = 96;       // FEAT=80 padded to 96

constexpr int N_G    = 1024;
constexpr int N_WT1  = 256 * 768;    // tw1 -> [256][768]
constexpr int N_WT2  = 256 * 256;
constexpr int N_WF1  = 256 * 288;    // fw1 -> [256][3*96]
constexpr int N_WF2  = 256 * 768;
constexpr int N_WF3  = 256 * 256;
constexpr int N_MHL  = B * PRF * CIN_M;   // 394752
constexpr int N_HHL  = B * PRH * D;       // 266240
constexpr int N_Y1P  = B * 2 * D;         // zero pad rows of y1
constexpr int PREP_TOTAL = N_G + N_WT1 + N_WT2 + N_WF1 + N_WF2 + N_WF3
                         + N_MHL + N_HHL + N_Y1P;

// ================= prep: gamma + weight/input conversion =================
__device__ __forceinline__ void wconv(const float* __restrict__ w,
                                      u16* __restrict__ oh, u16* __restrict__ ol,
                                      int I, int TAPS, int CINP, int idx) {
    int KTOT = TAPS * CINP;
    int o = idx / KTOT, kk = idx % KTOT;
    int tap = kk / CINP, ci = kk % CINP;
    float v = (ci < I) ? w[(o * I + ci) * TAPS + tap] : 0.f;
    split_store(v, oh, ol, idx);
}

__global__ __launch_bounds__(256) void k_prep(
    const float* __restrict__ m, const float* __restrict__ h,
    const float* __restrict__ tw1, const float* __restrict__ tw2,
    const float* __restrict__ fw1, const float* __restrict__ fw2,
    const float* __restrict__ fw3,
    float* __restrict__ gt,
    u16* __restrict__ WT1h, u16* __restrict__ WT1l,
    u16* __restrict__ WT2h, u16* __restrict__ WT2l,
    u16* __restrict__ WF1h, u16* __restrict__ WF1l,
    u16* __restrict__ WF2h, u16* __restrict__ WF2l,
    u16* __restrict__ WF3h, u16* __restrict__ WF3l,
    u16* __restrict__ Mh, u16* __restrict__ Ml,
    u16* __restrict__ Hh, u16* __restrict__ Hl,
    u16* __restrict__ Y1h, u16* __restrict__ Y1l)
{
    int idx = blockIdx.x * 256 + threadIdx.x;
    if (idx < N_G) { gt[idx] = (float)lgamma((double)idx); return; }
    idx -= N_G;
    if (idx < N_WT1) { wconv(tw1, WT1h, WT1l, 256, 3, 256, idx); return; }
    idx -= N_WT1;
    if (idx < N_WT2) { wconv(tw2, WT2h, WT2l, 256, 1, 256, idx); return; }
    idx -= N_WT2;
    if (idx < N_WF1) { wconv(fw1, WF1h, WF1l,  80, 3, CIN_M, idx); return; }
    idx -= N_WF1;
    if (idx < N_WF2) { wconv(fw2, WF2h, WF2l, 256, 3, 256, idx); return; }
    idx -= N_WF2;
    if (idx < N_WF3) { wconv(fw3, WF3h, WF3l, 256, 1, 256, idx); return; }
    idx -= N_WF3;
    if (idx < N_MHL) {
        int ci = idx % CIN_M;
        int p  = (idx / CIN_M) % PRF;
        int b  = idx / (CIN_M * PRF);
        float v = (p >= 1 && p <= F && ci < FEAT)
                ? m[(b * F + (p - 1)) * FEAT + ci] : 0.f;
        split_store(v, Mh, Ml, idx);
        return;
    }
    idx -= N_MHL;
    if (idx < N_HHL) {
        int ci = idx % D;
        int p  = (idx / D) % PRH;
        int b  = idx / (D * PRH);
        float v = (p >= 1 && p <= S) ? h[(b * S + (p - 1)) * D + ci] : 0.f;
        split_store(v, Hh, Hl, idx);
        return;
    }
    idx -= N_HHL;
    if (idx < N_Y1P) {   // zero the halo rows of y1 (rows 0 and PRF-1 per batch)
        int ci = idx % D;
        int which = (idx / D) & 1;
        int b = idx / (2 * D);
        int row = b * PRF + (which ? (PRF - 1) : 0);
        Y1h[row * D + ci] = 0;
        Y1l[row * D + ci] = 0;
    }
}

// ================= MFMA conv tile: 16 pos x 32 cout per wave =================
// A: act[row][k] with row stride == CINP so tap*CINP == next row.
// W: B^T layout [co][tap*CINP+ci], hi/lo planes.
// 3-term split MFMA: ah*bh + ah*bl + al*bh (fp32-grade).
// Unroll capped at 4 to keep in-flight loads ~24 (no spill).
template<int CINP, int TAPS, bool RELU, bool OUT_HL>
__device__ __forceinline__ void conv_tile(
    const u16* __restrict__ Ah, const u16* __restrict__ Al, int arowbase,
    const u16* __restrict__ Wh, const u16* __restrict__ Wl,
    const float* __restrict__ bias, int co0,
    float* __restrict__ outF, u16* __restrict__ Oh, u16* __restrict__ Ol,
    int orowbase)
{
    constexpr int KTOT = TAPS * CINP;
    constexpr int KSTEPS = KTOT / 32;
    constexpr int KPT = CINP / 32;     // k-steps per tap
    const int l  = threadIdx.x & 63;
    const int lr = l & 15;
    const int kg = l >> 4;

    f32x4 acc0 = {0.f, 0.f, 0.f, 0.f};
    f32x4 acc1 = acc0;

    const u16* arh = Ah + (arowbase + lr) * CINP + kg * 8;
    const u16* arl = Al + (arowbase + lr) * CINP + kg * 8;
    const u16* wh  = Wh + (co0 + lr) * KTOT + kg * 8;
    const u16* wl  = Wl + (co0 + lr) * KTOT + kg * 8;

#pragma unroll 4
    for (int kb = 0; kb < KSTEPS; ++kb) {
        const int aoff = (kb / KPT) * CINP + (kb % KPT) * 32;  // tap skips a row
        bf16x8 ah = *(const bf16x8*)(arh + aoff);
        bf16x8 al = *(const bf16x8*)(arl + aoff);
        const int wk = kb * 32;
        bf16x8 b0h = *(const bf16x8*)(wh + wk);
        bf16x8 b0l = *(const bf16x8*)(wl + wk);
        bf16x8 b1h = *(const bf16x8*)(wh + 16 * KTOT + wk);
        bf16x8 b1l = *(const bf16x8*)(wl + 16 * KTOT + wk);
        acc0 = __builtin_amdgcn_mfma_f32_16x16x32_bf16(ah, b0h, acc0, 0, 0, 0);
        acc1 = __builtin_amdgcn_mfma_f32_16x16x32_bf16(ah, b1h, acc1, 0, 0, 0);
        acc0 = __builtin_amdgcn_mfma_f32_16x16x32_bf16(ah, b0l, acc0, 0, 0, 0);
        acc1 = __builtin_amdgcn_mfma_f32_16x16x32_bf16(ah, b1l, acc1, 0, 0, 0);
        acc0 = __builtin_amdgcn_mfma_f32_16x16x32_bf16(al, b0h, acc0, 0, 0, 0);
        acc1 = __builtin_amdgcn_mfma_f32_16x16x32_bf16(al, b1h, acc1, 0, 0, 0);
    }

    const int orow = orowbase + kg * 4;
    {
        int co = co0 + lr;
        float bv = bias[co];
#pragma unroll
        for (int r = 0; r < 4; ++r) {
            float v = acc0[r] + bv;
            if (RELU) v = fmaxf(v, 0.f);
            int o = (orow + r) * 256 + co;
            if (OUT_HL) split_store(v, Oh, Ol, o);
            else        outF[o] = v;
        }
    }
    {
        int co = co0 + 16 + lr;
        float bv = bias[co];
#pragma unroll
        for (int r = 0; r < 4; ++r) {
            float v = acc1[r] + bv;
            if (RELU) v = fmaxf(v, 0.f);
            int o = (orow + r) * 256 + co;
            if (OUT_HL) split_store(v, Oh, Ol, o);
            else        outF[o] = v;
        }
    }
}

// ---- kernel A: f1 (2048 blocks) + t1 (512 blocks) ----
__global__ __launch_bounds__(64) void k_convA(
    const u16* __restrict__ Mh, const u16* __restrict__ Ml,
    const u16* __restrict__ Hh, const u16* __restrict__ Hl,
    const u16* __restrict__ WF1h, const u16* __restrict__ WF1l,
    const u16* __restrict__ WT1h, const u16* __restrict__ WT1l,
    const float* __restrict__ fb1, const float* __restrict__ tb1,
    u16* __restrict__ Y1h, u16* __restrict__ Y1l,
    u16* __restrict__ X1h, u16* __restrict__ X1l)
{
    int bid = blockIdx.x;
    if (bid < 2048) {   // f1: relu(conv3(m)) -> y1 (padded rows)
        int co0 = (bid & 7) * 32;
        int p0  = ((bid >> 3) & 31) * 16;
        int b   = bid >> 8;
        conv_tile<CIN_M, 3, true, true>(Mh, Ml, b * PRF + p0, WF1h, WF1l, fb1, co0,
                                        nullptr, Y1h, Y1l, b * PRF + p0 + 1);
    } else {            // t1: relu(conv3(h)) -> x1 (unpadded)
        int i = bid - 2048;
        int co0 = (i & 7) * 32;
        int p0  = ((i >> 3) & 7) * 16;
        int b   = i >> 6;
        conv_tile<D, 3, true, true>(Hh, Hl, b * PRH + p0, WT1h, WT1l, tb1, co0,
                                    nullptr, X1h, X1l, b * S + p0);
    }
}

// ---- kernel B: f2 (2048 blocks) ----
__global__ __launch_bounds__(64) void k_convB(
    const u16* __restrict__ Y1h, const u16* __restrict__ Y1l,
    const u16* __restrict__ WF2h, const u16* __restrict__ WF2l,
    const float* __restrict__ fb2,
    u16* __restrict__ Y2h, u16* __restrict__ Y2l)
{
    int bid = blockIdx.x;
    int co0 = (bid & 7) * 32;
    int p0  = ((bid >> 3) & 31) * 16;
    int b   = bid >> 8;
    conv_tile<D, 3, true, true>(Y1h, Y1l, b * PRF + p0, WF2h, WF2l, fb2, co0,
                                nullptr, Y2h, Y2l, b * F + p0);
}

// ---- kernel C: f3 (2048 blocks) + t2 (512 blocks) ----
__global__ __launch_bounds__(64) void k_convC(
    const u16* __restrict__ Y2h, const u16* __restrict__ Y2l,
    const u16* __restrict__ X1h, const u16* __restrict__ X1l,
    const u16* __restrict__ WF3h, const u16* __restrict__ WF3l,
    const u16* __restrict__ WT2h, const u16* __restrict__ WT2l,
    const float* __restrict__ fb3, const float* __restrict__ tb2,
    float* __restrict__ mm, float* __restrict__ hh)
{
    int bid = blockIdx.x;
    if (bid < 2048) {   // f3: conv1(y2) -> mm fp32
        int co0 = (bid & 7) * 32;
        int p0  = ((bid >> 3) & 31) * 16;
        int b   = bid >> 8;
        conv_tile<D, 1, false, false>(Y2h, Y2l, b * F + p0, WF3h, WF3l, fb3, co0,
                                      mm, nullptr, nullptr, b * F + p0);
    } else {            // t2: conv1(x1) -> hh fp32
        int i = bid - 2048;
        int co0 = (i & 7) * 32;
        int p0  = ((i >> 3) & 7) * 16;
        int b   = i >> 6;
        conv_tile<D, 1, false, false>(X1h, X1l, b * S + p0, WT2h, WT2l, tb2, co0,
                                      hh, nullptr, nullptr, b * S + p0);
    }
}

// ---------------- pairwise L2 distance ----------------
constexpr int TS = 32, TF = 64, TK = 32;
__global__ __launch_bounds__(256) void k_dist(
    const float* __restrict__ hh, const float* __restrict__ mm,
    float* __restrict__ scores)
{
    __shared__ float As[TS][TK + 1];
    __shared__ float Bs[TF][TK + 1];
    int t = threadIdx.x;
    constexpr int nf = F / TF;
    constexpr int ns = S / TS;
    int b = blockIdx.x / (nf * ns);
    int rem = blockIdx.x % (nf * ns);
    int s0 = (rem / nf) * TS;
    int f0 = (rem % nf) * TF;
    int tx = t & 15, ty = t >> 4;

    float c[2][4] = {};
    for (int k0 = 0; k0 < D; k0 += TK) {
        {
            int r = t / 8, c4 = (t % 8) * 4;
            float4 v = *(const float4*)&hh[(b * S + s0 + r) * D + k0 + c4];
            As[r][c4] = v.x; As[r][c4 + 1] = v.y; As[r][c4 + 2] = v.z; As[r][c4 + 3] = v.w;
        }
#pragma unroll
        for (int half = 0; half < 2; ++half) {
            int rr = half * 32 + t / 8, c4 = (t % 8) * 4;
            float4 v = *(const float4*)&mm[(b * F + f0 + rr) * D + k0 + c4];
            Bs[rr][c4] = v.x; Bs[rr][c4 + 1] = v.y; Bs[rr][c4 + 2] = v.z; Bs[rr][c4 + 3] = v.w;
        }
        __syncthreads();
#pragma unroll
        for (int k = 0; k < TK; ++k) {
            float a0 = As[ty * 2 + 0][k];
            float a1 = As[ty * 2 + 1][k];
            float b0 = Bs[tx * 4 + 0][k];
            float b1 = Bs[tx * 4 + 1][k];
            float b2 = Bs[tx * 4 + 2][k];
            float b3 = Bs[tx * 4 + 3][k];
            float d;
            d = a0 - b0; c[0][0] = fmaf(d, d, c[0][0]);
            d = a0 - b1; c[0][1] = fmaf(d, d, c[0][1]);
            d = a0 - b2; c[0][2] = fmaf(d, d, c[0][2]);
            d = a0 - b3; c[0][3] = fmaf(d, d, c[0][3]);
            d = a1 - b0; c[1][0] = fmaf(d, d, c[1][0]);
            d = a1 - b1; c[1][1] = fmaf(d, d, c[1][1]);
            d = a1 - b2; c[1][2] = fmaf(d, d, c[1][2]);
            d = a1 - b3; c[1][3] = fmaf(d, d, c[1][3]);
        }
        __syncthreads();
    }
#pragma unroll
    for (int i = 0; i < 2; ++i) {
        int s = s0 + ty * 2 + i;
        float4 v;
        v.x = -sqrtf(fmaxf(c[i][0], 0.f));
        v.y = -sqrtf(fmaxf(c[i][1], 0.f));
        v.z = -sqrtf(fmaxf(c[i][2], 0.f));
        v.w = -sqrtf(fmaxf(c[i][3], 0.f));
        *(float4*)&scores[(b * S + s) * F + f0 + tx * 4] = v;
    }
}

// ---------------- softmax over S + beta-binomial prior (in-place on d_out) ----------------
__global__ __launch_bounds__(256) void k_soft(
    const float* __restrict__ gt,
    const int* __restrict__ tok_len, const int* __restrict__ feat_len,
    float* __restrict__ out)
{
    __shared__ float gts[1024];
    __shared__ float red[256];
    int t = threadIdx.x;
    int b = blockIdx.x / (F / 64);
    int f0 = (blockIdx.x % (F / 64)) * 64;
    int fi = t & 63, sg = t >> 6;
    int f = f0 + fi;
    for (int i = t; i < 1024; i += 256) gts[i] = gt[i];
    int L = tok_len[b], Fl = feat_len[b];

    float sv[32];
    float mx = -INFINITY;
#pragma unroll
    for (int i = 0; i < 32; ++i) {
        int s = sg + i * 4;
        float v = out[(b * S + s) * F + f];
        if (s >= L) v = -INFINITY;
        sv[i] = v;
        mx = fmaxf(mx, v);
    }
    red[t] = mx;
    __syncthreads();
    float m = fmaxf(fmaxf(red[fi], red[64 + fi]), fmaxf(red[128 + fi], red[192 + fi]));
    __syncthreads();
    float sum = 0.f;
#pragma unroll
    for (int i = 0; i < 32; ++i) sum += expf(sv[i] - m);
    red[t] = sum;
    __syncthreads();
    float tot = red[fi] + red[64 + fi] + red[128 + fi] + red[192 + fi];
    float lse = m + logf(tot);

    float cb = gts[L] - gts[L + Fl] + gts[Fl + 1];
    bool fvalid = f < Fl;
    float cf = fvalid ? (-gts[f + 1] - gts[Fl - f]) : 0.f;
#pragma unroll
    for (int i = 0; i < 32; ++i) {
        int s = sg + i * 4;
        float o;
        if (s >= L || !fvalid) {
            o = NEG_HUGE;
        } else {
            float lp = cb + cf - gts[s + 1] - gts[L - s]
                     + gts[s + f + 1] + gts[L - 1 - s + Fl - f];
            o = lp + sv[i] - lse;
        }
        out[(b * S + s) * F + f] = o;
    }
}

extern "C" void kernel_launch(void* const* d_in, const int* in_sizes, int n_in,
                              void* d_out, int out_size, void* d_ws, size_t ws_size,
                              hipStream_t stream)
{
    const float* h   = (const float*)d_in[0];
    const float* m_  = (const float*)d_in[1];
    const float* tw1 = (const float*)d_in[2];
    const float* tb1 = (const float*)d_in[3];
    const float* tw2 = (const float*)d_in[4];
    const float* tb2 = (const float*)d_in[5];
    const float* fw1 = (const float*)d_in[6];
    const float* fb1 = (const float*)d_in[7];
    const float* fw2 = (const float*)d_in[8];
    const float* fb2 = (const float*)d_in[9];
    const float* fw3 = (const float*)d_in[10];
    const float* fb3 = (const float*)d_in[11];
    const int* tokl  = (const int*)d_in[13];
    const int* featl = (const int*)d_in[14];

    char* base = (char*)d_ws;
    size_t off = 0;
    auto alloc = [&](size_t bytes) -> char* {
        size_t a = (off + 255) & ~(size_t)255;
        off = a + bytes;
        return base + a;
    };

    float* gt  = (float*)alloc(N_G * 4);
    u16* WT1h = (u16*)alloc(N_WT1 * 2); u16* WT1l = (u16*)alloc(N_WT1 * 2);
    u16* WT2h = (u16*)alloc(N_WT2 * 2); u16* WT2l = (u16*)alloc(N_WT2 * 2);
    u16* WF1h = (u16*)alloc(N_WF1 * 2); u16* WF1l = (u16*)alloc(N_WF1 * 2);
    u16* WF2h = (u16*)alloc(N_WF2 * 2); u16* WF2l = (u16*)alloc(N_WF2 * 2);
    u16* WF3h = (u16*)alloc(N_WF3 * 2); u16* WF3l = (u16*)alloc(N_WF3 * 2);
    u16* Mh   = (u16*)alloc(N_MHL * 2); u16* Ml   = (u16*)alloc(N_MHL * 2);
    u16* Hh   = (u16*)alloc(N_HHL * 2); u16* Hl   = (u16*)alloc(N_HHL * 2);
    u16* Y1h  = (u16*)alloc(B * PRF * D * 2); u16* Y1l = (u16*)alloc(B * PRF * D * 2);
    u16* Y2h  = (u16*)alloc(B * F * D * 2);   u16* Y2l = (u16*)alloc(B * F * D * 2);
    u16* X1h  = (u16*)alloc(B * S * D * 2);   u16* X1l = (u16*)alloc(B * S * D * 2);
    float* mm = (float*)alloc(B * F * D * 4);
    float* hh = (float*)alloc(B * S * D * 4);
    float* out = (float*)d_out;

    k_prep<<<(PREP_TOTAL + 255) / 256, 256, 0, stream>>>(
        m_, h, tw1, tw2, fw1, fw2, fw3, gt,
        WT1h, WT1l, WT2h, WT2l, WF1h, WF1l, WF2h, WF2l, WF3h, WF3l,
        Mh, Ml, Hh, Hl, Y1h, Y1l);

    k_convA<<<2560, 64, 0, stream>>>(Mh, Ml, Hh, Hl, WF1h, WF1l, WT1h, WT1l,
                                     fb1, tb1, Y1h, Y1l, X1h, X1l);
    k_convB<<<2048, 64, 0, stream>>>(Y1h, Y1l, WF2h, WF2l, fb2, Y2h, Y2l);
    k_convC<<<2560, 64, 0, stream>>>(Y2h, Y2l, X1h, X1l, WF3h, WF3l, WT2h, WT2l,
                                     fb3, tb2, mm, hh);

    k_dist<<<B * (S / TS) * (F / TF), 256, 0, stream>>>(hh, mm, out);
    k_soft<<<B * (F / 64), 256, 0, stream>>>(gt, tokl, featl, out);
}

// Round 8
// 106.284 us; speedup vs baseline: 1.0766x; 1.0766x over previous
//
#include <hip/hip_runtime.h>
#include <cmath>

constexpr int B = 8, S = 128, F = 512, D = 256, FEAT = 80;
// Finite stand-in for -inf (see round-1 note: avoids nan in harness absmax).
#define NEG_HUGE (-3.0e38f)

typedef unsigned short u16;
typedef unsigned int u32;
typedef __attribute__((ext_vector_type(8))) short bf16x8;   // 8 bf16 = 4 VGPR
typedef __attribute__((ext_vector_type(4))) float f32x4;

#define MFMA(a, b, c) __builtin_amdgcn_mfma_f32_16x16x32_bf16((a), (b), (c), 0, 0, 0)

// ---- bf16 split helpers ----
__device__ __forceinline__ u16 f2bf(float x) {
    u32 u = __float_as_uint(x);
    u32 r = (u + 0x7fffu + ((u >> 16) & 1u)) >> 16;   // RNE
    return (u16)r;
}
__device__ __forceinline__ float bf2f(u16 s) {
    return __uint_as_float(((u32)s) << 16);
}
__device__ __forceinline__ void split_store(float v, u16* __restrict__ hi,
                                            u16* __restrict__ lo, int idx) {
    u16 h = f2bf(v);
    hi[idx] = h;
    lo[idx] = f2bf(v - bf2f(h));
}

// ================= sizes =================
constexpr int PRF = F + 2;      // 514 padded feat rows
constexpr int PRH = S + 2;      // 130 padded text rows
constexpr int CIN_M = 96;       // FEAT=80 padded to 96

constexpr int N_G    = 1024;
constexpr int N_WT1  = 256 * 768;
constexpr int N_WT2  = 256 * 256;
constexpr int N_WF1  = 256 * 288;
constexpr int N_WF2  = 256 * 768;
constexpr int N_WF3  = 256 * 256;
constexpr int N_MHL  = B * PRF * CIN_M;
constexpr int N_HHL  = B * PRH * D;
constexpr int N_Y1P  = B * 2 * D;
constexpr int PREP_TOTAL = N_G + N_WT1 + N_WT2 + N_WF1 + N_WF2 + N_WF3
                         + N_MHL + N_HHL + N_Y1P;

// ================= prep: gamma + weight/input conversion =================
__device__ __forceinline__ void wconv(const float* __restrict__ w,
                                      u16* __restrict__ oh, u16* __restrict__ ol,
                                      int I, int TAPS, int CINP, int idx) {
    int KTOT = TAPS * CINP;
    int o = idx / KTOT, kk = idx % KTOT;
    int tap = kk / CINP, ci = kk % CINP;
    float v = (ci < I) ? w[(o * I + ci) * TAPS + tap] : 0.f;
    split_store(v, oh, ol, idx);
}

__global__ __launch_bounds__(256) void k_prep(
    const float* __restrict__ m, const float* __restrict__ h,
    const float* __restrict__ tw1, const float* __restrict__ tw2,
    const float* __restrict__ fw1, const float* __restrict__ fw2,
    const float* __restrict__ fw3,
    float* __restrict__ gt,
    u16* __restrict__ WT1h, u16* __restrict__ WT1l,
    u16* __restrict__ WT2h, u16* __restrict__ WT2l,
    u16* __restrict__ WF1h, u16* __restrict__ WF1l,
    u16* __restrict__ WF2h, u16* __restrict__ WF2l,
    u16* __restrict__ WF3h, u16* __restrict__ WF3l,
    u16* __restrict__ Mh, u16* __restrict__ Ml,
    u16* __restrict__ Hh, u16* __restrict__ Hl,
    u16* __restrict__ Y1h, u16* __restrict__ Y1l)
{
    int idx = blockIdx.x * 256 + threadIdx.x;
    if (idx < N_G) { gt[idx] = (float)lgamma((double)idx); return; }
    idx -= N_G;
    if (idx < N_WT1) { wconv(tw1, WT1h, WT1l, 256, 3, 256, idx); return; }
    idx -= N_WT1;
    if (idx < N_WT2) { wconv(tw2, WT2h, WT2l, 256, 1, 256, idx); return; }
    idx -= N_WT2;
    if (idx < N_WF1) { wconv(fw1, WF1h, WF1l,  80, 3, CIN_M, idx); return; }
    idx -= N_WF1;
    if (idx < N_WF2) { wconv(fw2, WF2h, WF2l, 256, 3, 256, idx); return; }
    idx -= N_WF2;
    if (idx < N_WF3) { wconv(fw3, WF3h, WF3l, 256, 1, 256, idx); return; }
    idx -= N_WF3;
    if (idx < N_MHL) {
        int ci = idx % CIN_M;
        int p  = (idx / CIN_M) % PRF;
        int b  = idx / (CIN_M * PRF);
        float v = (p >= 1 && p <= F && ci < FEAT)
                ? m[(b * F + (p - 1)) * FEAT + ci] : 0.f;
        split_store(v, Mh, Ml, idx);
        return;
    }
    idx -= N_MHL;
    if (idx < N_HHL) {
        int ci = idx % D;
        int p  = (idx / D) % PRH;
        int b  = idx / (D * PRH);
        float v = (p >= 1 && p <= S) ? h[(b * S + (p - 1)) * D + ci] : 0.f;
        split_store(v, Hh, Hl, idx);
        return;
    }
    idx -= N_HHL;
    if (idx < N_Y1P) {
        int ci = idx % D;
        int which = (idx / D) & 1;
        int b = idx / (2 * D);
        int row = b * PRF + (which ? (PRF - 1) : 0);
        Y1h[row * D + ci] = 0;
        Y1l[row * D + ci] = 0;
    }
}

// ================= MFMA conv tile: 32 pos x 64 cout per wave =================
// A: act[row][k], row stride CINP (tap advance == +1 row). W: [co][tap*CINP+ci].
// 3-term split: ah*bh + ah*bl + al*bh. Output always hi/lo bf16 planes.
template<int CINP, int TAPS, bool RELU>
__device__ __forceinline__ void conv_tile32(
    const u16* __restrict__ Ah, const u16* __restrict__ Al, int arowbase,
    const u16* __restrict__ Wh, const u16* __restrict__ Wl,
    const float* __restrict__ bias, int co0,
    u16* __restrict__ Oh, u16* __restrict__ Ol, int orowbase)
{
    constexpr int KTOT = TAPS * CINP;
    constexpr int KSTEPS = KTOT / 32;
    constexpr int KPT = CINP / 32;
    const int l  = threadIdx.x & 63;
    const int lr = l & 15;
    const int kg = l >> 4;

    f32x4 acc[2][4];
#pragma unroll
    for (int m2 = 0; m2 < 2; ++m2)
#pragma unroll
        for (int ct = 0; ct < 4; ++ct)
            acc[m2][ct] = f32x4{0.f, 0.f, 0.f, 0.f};

    const u16* a0h = Ah + (arowbase + lr) * CINP + kg * 8;
    const u16* a0l = Al + (arowbase + lr) * CINP + kg * 8;
    const u16* wh  = Wh + (co0 + lr) * KTOT + kg * 8;
    const u16* wl  = Wl + (co0 + lr) * KTOT + kg * 8;

#pragma unroll 2
    for (int kb = 0; kb < KSTEPS; ++kb) {
        const int aoff = (kb / KPT) * CINP + (kb % KPT) * 32;  // tap = +1 row
        const int wk = kb * 32;
        bf16x8 ah0 = *(const bf16x8*)(a0h + aoff);
        bf16x8 al0 = *(const bf16x8*)(a0l + aoff);
        bf16x8 ah1 = *(const bf16x8*)(a0h + 16 * CINP + aoff);
        bf16x8 al1 = *(const bf16x8*)(a0l + 16 * CINP + aoff);
#pragma unroll
        for (int ct = 0; ct < 4; ++ct) {
            bf16x8 bh = *(const bf16x8*)(wh + ct * 16 * KTOT + wk);
            bf16x8 bl = *(const bf16x8*)(wl + ct * 16 * KTOT + wk);
            acc[0][ct] = MFMA(ah0, bh, acc[0][ct]);
            acc[0][ct] = MFMA(ah0, bl, acc[0][ct]);
            acc[0][ct] = MFMA(al0, bh, acc[0][ct]);
            acc[1][ct] = MFMA(ah1, bh, acc[1][ct]);
            acc[1][ct] = MFMA(ah1, bl, acc[1][ct]);
            acc[1][ct] = MFMA(al1, bh, acc[1][ct]);
        }
    }

#pragma unroll
    for (int m2 = 0; m2 < 2; ++m2) {
        int orow = orowbase + m2 * 16 + kg * 4;
#pragma unroll
        for (int ct = 0; ct < 4; ++ct) {
            int co = co0 + ct * 16 + lr;
            float bv = bias[co];
#pragma unroll
            for (int r = 0; r < 4; ++r) {
                float v = acc[m2][ct][r] + bv;
                if (RELU) v = fmaxf(v, 0.f);
                split_store(v, Oh, Ol, (orow + r) * 256 + co);
            }
        }
    }
}

// ---- kernel A: f1 (512 blocks) + t1 (128 blocks) ----
__global__ __launch_bounds__(64) void k_convA(
    const u16* __restrict__ Mh, const u16* __restrict__ Ml,
    const u16* __restrict__ Hh, const u16* __restrict__ Hl,
    const u16* __restrict__ WF1h, const u16* __restrict__ WF1l,
    const u16* __restrict__ WT1h, const u16* __restrict__ WT1l,
    const float* __restrict__ fb1, const float* __restrict__ tb1,
    u16* __restrict__ Y1h, u16* __restrict__ Y1l,
    u16* __restrict__ X1h, u16* __restrict__ X1l)
{
    int bid = blockIdx.x;
    if (bid < 512) {    // f1: relu(conv3(m)) -> y1 (padded rows)
        int co0 = (bid & 3) * 64;
        int p0  = ((bid >> 2) & 15) * 32;
        int b   = bid >> 6;
        conv_tile32<CIN_M, 3, true>(Mh, Ml, b * PRF + p0, WF1h, WF1l, fb1, co0,
                                    Y1h, Y1l, b * PRF + p0 + 1);
    } else {            // t1: relu(conv3(h)) -> x1
        int i = bid - 512;
        int co0 = (i & 3) * 64;
        int p0  = ((i >> 2) & 3) * 32;
        int b   = i >> 4;
        conv_tile32<D, 3, true>(Hh, Hl, b * PRH + p0, WT1h, WT1l, tb1, co0,
                                X1h, X1l, b * S + p0);
    }
}

// ---- kernel B: f2 (512 blocks) ----
__global__ __launch_bounds__(64) void k_convB(
    const u16* __restrict__ Y1h, const u16* __restrict__ Y1l,
    const u16* __restrict__ WF2h, const u16* __restrict__ WF2l,
    const float* __restrict__ fb2,
    u16* __restrict__ Y2h, u16* __restrict__ Y2l)
{
    int bid = blockIdx.x;
    int co0 = (bid & 3) * 64;
    int p0  = ((bid >> 2) & 15) * 32;
    int b   = bid >> 6;
    conv_tile32<D, 3, true>(Y1h, Y1l, b * PRF + p0, WF2h, WF2l, fb2, co0,
                            Y2h, Y2l, b * F + p0);
}

// ---- kernel C: f3 (512 blocks) + t2 (128 blocks), outputs hi/lo planes ----
__global__ __launch_bounds__(64) void k_convC(
    const u16* __restrict__ Y2h, const u16* __restrict__ Y2l,
    const u16* __restrict__ X1h, const u16* __restrict__ X1l,
    const u16* __restrict__ WF3h, const u16* __restrict__ WF3l,
    const u16* __restrict__ WT2h, const u16* __restrict__ WT2l,
    const float* __restrict__ fb3, const float* __restrict__ tb2,
    u16* __restrict__ Moh, u16* __restrict__ Mol,
    u16* __restrict__ Hoh, u16* __restrict__ Hol)
{
    int bid = blockIdx.x;
    if (bid < 512) {    // f3: conv1(y2) -> Mo
        int co0 = (bid & 3) * 64;
        int p0  = ((bid >> 2) & 15) * 32;
        int b   = bid >> 6;
        conv_tile32<D, 1, false>(Y2h, Y2l, b * F + p0, WF3h, WF3l, fb3, co0,
                                 Moh, Mol, b * F + p0);
    } else {            // t2: conv1(x1) -> Ho
        int i = bid - 512;
        int co0 = (i & 3) * 64;
        int p0  = ((i >> 2) & 3) * 32;
        int b   = i >> 4;
        conv_tile32<D, 1, false>(X1h, X1l, b * S + p0, WT2h, WT2l, tb2, co0,
                                 Hoh, Hol, b * S + p0);
    }
}

// ---------------- distance via MFMA: dist2 = na + nb - 2 ab ----------------
// Block: 32 s x 64 f, 256 thr (4 waves; wave w = 16-f slice). scores fp32.
__global__ __launch_bounds__(256) void k_dist2(
    const u16* __restrict__ Hoh, const u16* __restrict__ Hol,
    const u16* __restrict__ Moh, const u16* __restrict__ Mol,
    float* __restrict__ scores)
{
    __shared__ float red[256];
    __shared__ float naA[32];
    __shared__ float nbA[64];
    int t = threadIdx.x;
    int blk = blockIdx.x;
    int b = blk >> 5;
    int rem = blk & 31;
    int s0 = (rem >> 3) * 32;
    int f0 = (rem & 7) * 64;

    // ---- na[32]: row norms of X
    {
        int r = t >> 3, kc = (t & 7) * 32;
        const u16* ph = Hoh + (b * S + s0 + r) * 256 + kc;
        const u16* pl = Hol + (b * S + s0 + r) * 256 + kc;
        float s = 0.f;
#pragma unroll
        for (int j = 0; j < 4; ++j) {
            bf16x8 hv = *(const bf16x8*)(ph + j * 8);
            bf16x8 lv = *(const bf16x8*)(pl + j * 8);
#pragma unroll
            for (int e = 0; e < 8; ++e) {
                float a = bf2f((u16)hv[e]) + bf2f((u16)lv[e]);
                s = fmaf(a, a, s);
            }
        }
        red[t] = s;
    }
    __syncthreads();
    if (t < 32) {
        float s = 0.f;
#pragma unroll
        for (int j = 0; j < 8; ++j) s += red[t * 8 + j];
        naA[t] = s;
    }
    __syncthreads();
    // ---- nb[64]: row norms of M
    {
        int c = t >> 2, kc = (t & 3) * 64;
        const u16* ph = Moh + (b * F + f0 + c) * 256 + kc;
        const u16* pl = Mol + (b * F + f0 + c) * 256 + kc;
        float s = 0.f;
#pragma unroll
        for (int j = 0; j < 8; ++j) {
            bf16x8 hv = *(const bf16x8*)(ph + j * 8);
            bf16x8 lv = *(const bf16x8*)(pl + j * 8);
#pragma unroll
            for (int e = 0; e < 8; ++e) {
                float a = bf2f((u16)hv[e]) + bf2f((u16)lv[e]);
                s = fmaf(a, a, s);
            }
        }
        red[t] = s;
    }
    __syncthreads();
    if (t < 64) {
        float s = 0.f;
#pragma unroll
        for (int j = 0; j < 4; ++j) s += red[t * 4 + j];
        nbA[t] = s;
    }
    __syncthreads();

    // ---- ab via 3-term split MFMA
    int w = t >> 6, l = t & 63, lr = l & 15, kg = l >> 4;
    f32x4 acc0 = {0.f, 0.f, 0.f, 0.f};
    f32x4 acc1 = acc0;
    const u16* xh = Hoh + (b * S + s0 + lr) * 256 + kg * 8;
    const u16* xl = Hol + (b * S + s0 + lr) * 256 + kg * 8;
    const u16* mh = Moh + (b * F + f0 + w * 16 + lr) * 256 + kg * 8;
    const u16* ml = Mol + (b * F + f0 + w * 16 + lr) * 256 + kg * 8;
#pragma unroll 2
    for (int kb = 0; kb < 8; ++kb) {
        int ko = kb * 32;
        bf16x8 ah0 = *(const bf16x8*)(xh + ko);
        bf16x8 al0 = *(const bf16x8*)(xl + ko);
        bf16x8 ah1 = *(const bf16x8*)(xh + 16 * 256 + ko);
        bf16x8 al1 = *(const bf16x8*)(xl + 16 * 256 + ko);
        bf16x8 bh  = *(const bf16x8*)(mh + ko);
        bf16x8 bl  = *(const bf16x8*)(ml + ko);
        acc0 = MFMA(ah0, bh, acc0);
        acc0 = MFMA(ah0, bl, acc0);
        acc0 = MFMA(al0, bh, acc0);
        acc1 = MFMA(ah1, bh, acc1);
        acc1 = MFMA(ah1, bl, acc1);
        acc1 = MFMA(al1, bh, acc1);
    }

    // ---- combine + write: D col=lane&15 -> f, row=(lane>>4)*4+r -> s
#pragma unroll
    for (int m2 = 0; m2 < 2; ++m2) {
#pragma unroll
        for (int r = 0; r < 4; ++r) {
            int sl = m2 * 16 + kg * 4 + r;
            int fl = w * 16 + lr;
            float ab = m2 ? acc1[r] : acc0[r];
            float d2 = naA[sl] + nbA[fl] - 2.f * ab;
            scores[(b * S + s0 + sl) * F + f0 + fl] = -sqrtf(fmaxf(d2, 0.f));
        }
    }
}

// ---------------- softmax over S + beta-binomial prior (in-place on d_out) ----------------
__global__ __launch_bounds__(256) void k_soft(
    const float* __restrict__ gt,
    const int* __restrict__ tok_len, const int* __restrict__ feat_len,
    float* __restrict__ out)
{
    __shared__ float gts[1024];
    __shared__ float red[256];
    int t = threadIdx.x;
    int b = blockIdx.x / (F / 64);
    int f0 = (blockIdx.x % (F / 64)) * 64;
    int fi = t & 63, sg = t >> 6;
    int f = f0 + fi;
    for (int i = t; i < 1024; i += 256) gts[i] = gt[i];
    int L = tok_len[b], Fl = feat_len[b];

    float sv[32];
    float mx = -INFINITY;
#pragma unroll
    for (int i = 0; i < 32; ++i) {
        int s = sg + i * 4;
        float v = out[(b * S + s) * F + f];
        if (s >= L) v = -INFINITY;
        sv[i] = v;
        mx = fmaxf(mx, v);
    }
    red[t] = mx;
    __syncthreads();
    float m = fmaxf(fmaxf(red[fi], red[64 + fi]), fmaxf(red[128 + fi], red[192 + fi]));
    __syncthreads();
    float sum = 0.f;
#pragma unroll
    for (int i = 0; i < 32; ++i) sum += expf(sv[i] - m);
    red[t] = sum;
    __syncthreads();
    float tot = red[fi] + red[64 + fi] + red[128 + fi] + red[192 + fi];
    float lse = m + logf(tot);

    float cb = gts[L] - gts[L + Fl] + gts[Fl + 1];
    bool fvalid = f < Fl;
    float cf = fvalid ? (-gts[f + 1] - gts[Fl - f]) : 0.f;
#pragma unroll
    for (int i = 0; i < 32; ++i) {
        int s = sg + i * 4;
        float o;
        if (s >= L || !fvalid) {
            o = NEG_HUGE;
        } else {
            float lp = cb + cf - gts[s + 1] - gts[L - s]
                     + gts[s + f + 1] + gts[L - 1 - s + Fl - f];
            o = lp + sv[i] - lse;
        }
        out[(b * S + s) * F + f] = o;
    }
}

extern "C" void kernel_launch(void* const* d_in, const int* in_sizes, int n_in,
                              void* d_out, int out_size, void* d_ws, size_t ws_size,
                              hipStream_t stream)
{
    const float* h   = (const float*)d_in[0];
    const float* m_  = (const float*)d_in[1];
    const float* tw1 = (const float*)d_in[2];
    const float* tb1 = (const float*)d_in[3];
    const float* tw2 = (const float*)d_in[4];
    const float* tb2 = (const float*)d_in[5];
    const float* fw1 = (const float*)d_in[6];
    const float* fb1 = (const float*)d_in[7];
    const float* fw2 = (const float*)d_in[8];
    const float* fb2 = (const float*)d_in[9];
    const float* fw3 = (const float*)d_in[10];
    const float* fb3 = (const float*)d_in[11];
    const int* tokl  = (const int*)d_in[13];
    const int* featl = (const int*)d_in[14];

    char* base = (char*)d_ws;
    size_t off = 0;
    auto alloc = [&](size_t bytes) -> char* {
        size_t a = (off + 255) & ~(size_t)255;
        off = a + bytes;
        return base + a;
    };

    float* gt  = (float*)alloc(N_G * 4);
    u16* WT1h = (u16*)alloc(N_WT1 * 2); u16* WT1l = (u16*)alloc(N_WT1 * 2);
    u16* WT2h = (u16*)alloc(N_WT2 * 2); u16* WT2l = (u16*)alloc(N_WT2 * 2);
    u16* WF1h = (u16*)alloc(N_WF1 * 2); u16* WF1l = (u16*)alloc(N_WF1 * 2);
    u16* WF2h = (u16*)alloc(N_WF2 * 2); u16* WF2l = (u16*)alloc(N_WF2 * 2);
    u16* WF3h = (u16*)alloc(N_WF3 * 2); u16* WF3l = (u16*)alloc(N_WF3 * 2);
    u16* Mh   = (u16*)alloc(N_MHL * 2); u16* Ml   = (u16*)alloc(N_MHL * 2);
    u16* Hh   = (u16*)alloc(N_HHL * 2); u16* Hl   = (u16*)alloc(N_HHL * 2);
    u16* Y1h  = (u16*)alloc(B * PRF * D * 2); u16* Y1l = (u16*)alloc(B * PRF * D * 2);
    u16* Y2h  = (u16*)alloc(B * F * D * 2);   u16* Y2l = (u16*)alloc(B * F * D * 2);
    u16* X1h  = (u16*)alloc(B * S * D * 2);   u16* X1l = (u16*)alloc(B * S * D * 2);
    u16* Moh  = (u16*)alloc(B * F * D * 2);   u16* Mol = (u16*)alloc(B * F * D * 2);
    u16* Hoh  = (u16*)alloc(B * S * D * 2);   u16* Hol = (u16*)alloc(B * S * D * 2);
    float* out = (float*)d_out;

    k_prep<<<(PREP_TOTAL + 255) / 256, 256, 0, stream>>>(
        m_, h, tw1, tw2, fw1, fw2, fw3, gt,
        WT1h, WT1l, WT2h, WT2l, WF1h, WF1l, WF2h, WF2l, WF3h, WF3l,
        Mh, Ml, Hh, Hl, Y1h, Y1l);

    k_convA<<<640, 64, 0, stream>>>(Mh, Ml, Hh, Hl, WF1h, WF1l, WT1h, WT1l,
                                    fb1, tb1, Y1h, Y1l, X1h, X1l);
    k_convB<<<512, 64, 0, stream>>>(Y1h, Y1l, WF2h, WF2l, fb2, Y2h, Y2l);
    k_convC<<<640, 64, 0, stream>>>(Y2h, Y2l, X1h, X1l, WF3h, WF3l, WT2h, WT2l,
                                    fb3, tb2, Moh, Mol, Hoh, Hol);

    k_dist2<<<B * 32, 256, 0, stream>>>(Hoh, Hol, Moh, Mol, out);
    k_soft<<<B * (F / 64), 256, 0, stream>>>(gt, tokl, featl, out);
}